// Round 1
// baseline (974.537 us; speedup 1.0000x reference)
//
#include <hip/hip_runtime.h>

#define FEATS    64
#define CLASSES  16
#define EMB_DIM  7
#define ADJ_HID  11
#define DIFF     0.9f

// ---------------- graph preprocessing ----------------

__global__ __launch_bounds__(256) void k_deg(const int* __restrict__ dst, int* __restrict__ deg, int e) {
    int i = blockIdx.x * 256 + threadIdx.x;
    if (i < e) atomicAdd(&deg[dst[i]], 1);
}

__global__ __launch_bounds__(256) void k_invs(const int* __restrict__ deg, float* __restrict__ invs, int n) {
    int i = blockIdx.x * 256 + threadIdx.x;
    if (i < n) { int d = deg[i]; invs[i] = d > 0 ? rsqrtf((float)d) : 0.f; }
}

__global__ __launch_bounds__(256) void k_scan1(const int* __restrict__ deg, int* __restrict__ rowptr,
                                               int* __restrict__ bsum, int n) {
    __shared__ int s[256];
    int tid = threadIdx.x;
    int i = blockIdx.x * 256 + tid;
    int v = (i < n) ? deg[i] : 0;
    s[tid] = v; __syncthreads();
    for (int ofs = 1; ofs < 256; ofs <<= 1) {
        int t = (tid >= ofs) ? s[tid - ofs] : 0;
        __syncthreads(); s[tid] += t; __syncthreads();
    }
    if (i < n) rowptr[i] = s[tid] - v;              // exclusive within block
    if (tid == 255) bsum[blockIdx.x] = s[255];      // block total
}

__global__ __launch_bounds__(256) void k_scan2(int* __restrict__ bsum, int nb) {
    __shared__ int s[256];
    int tid = threadIdx.x;
    int v = (tid < nb) ? bsum[tid] : 0;
    s[tid] = v; __syncthreads();
    for (int ofs = 1; ofs < 256; ofs <<= 1) {
        int t = (tid >= ofs) ? s[tid - ofs] : 0;
        __syncthreads(); s[tid] += t; __syncthreads();
    }
    if (tid < nb) bsum[tid] = s[tid] - v;           // exclusive block offsets
}

__global__ __launch_bounds__(256) void k_scan3(int* __restrict__ rowptr, const int* __restrict__ bsum,
                                               int n, int e) {
    int i = blockIdx.x * 256 + threadIdx.x;
    if (i < n) rowptr[i] += bsum[i >> 8];
    if (i == n) rowptr[n] = e;
}

__global__ __launch_bounds__(256) void k_scatter(const int* __restrict__ src, const int* __restrict__ dst,
                                                 const float* __restrict__ invs, const int* __restrict__ rowptr,
                                                 int* __restrict__ cnt, int* __restrict__ ssrc,
                                                 float* __restrict__ snorm, int e) {
    int i = blockIdx.x * 256 + threadIdx.x;
    if (i >= e) return;
    int d = dst[i], sv = src[i];
    int pos = rowptr[d] + atomicAdd(&cnt[d], 1);
    ssrc[pos]  = sv;
    snorm[pos] = invs[sv] * invs[d];
}

// ---------------- diffusion convs (pull, CSR) ----------------

__global__ __launch_bounds__(256) void k_conv64(const float* __restrict__ zin, const float* __restrict__ h0,
                                                float* __restrict__ zout, const int* __restrict__ rowptr,
                                                const int* __restrict__ ssrc, const float* __restrict__ snorm,
                                                int n) {
    int g = blockIdx.x * 256 + threadIdx.x;
    int node = g >> 6;
    if (node >= n) return;
    int f = g & 63;
    int e0 = rowptr[node], e1 = rowptr[node + 1];
    float a0 = 0.f, a1 = 0.f;
    int e = e0;
    for (; e + 1 < e1; e += 2) {
        int   s0 = ssrc[e],  s1 = ssrc[e + 1];
        float w0 = snorm[e], w1 = snorm[e + 1];
        a0 = fmaf(w0, zin[(size_t)s0 * 64 + f], a0);
        a1 = fmaf(w1, zin[(size_t)s1 * 64 + f], a1);
    }
    if (e < e1) a0 = fmaf(snorm[e], zin[(size_t)ssrc[e] * 64 + f], a0);
    zout[(size_t)node * 64 + f] = (a0 + a1) * DIFF + (1.f - DIFF) * h0[(size_t)node * 64 + f];
}

__global__ __launch_bounds__(256) void k_conv16(const float* __restrict__ zin, const float* __restrict__ g0,
                                                float* __restrict__ zout, const int* __restrict__ rowptr,
                                                const int* __restrict__ ssrc, const float* __restrict__ snorm,
                                                int n) {
    int g = blockIdx.x * 256 + threadIdx.x;
    int node = g >> 4;
    if (node >= n) return;
    int f = g & 15;
    int e0 = rowptr[node], e1 = rowptr[node + 1];
    float a0 = 0.f, a1 = 0.f;
    int e = e0;
    for (; e + 1 < e1; e += 2) {
        int   s0 = ssrc[e],  s1 = ssrc[e + 1];
        float w0 = snorm[e], w1 = snorm[e + 1];
        a0 = fmaf(w0, zin[(size_t)s0 * 16 + f], a0);
        a1 = fmaf(w1, zin[(size_t)s1 * 16 + f], a1);
    }
    if (e < e1) a0 = fmaf(snorm[e], zin[(size_t)ssrc[e] * 16 + f], a0);
    zout[(size_t)node * 16 + f] = (a0 + a1) * DIFF + (1.f - DIFF) * g0[(size_t)node * 16 + f];
}

// ---------------- per-(node,feat) pair MLP ----------------

__global__ __launch_bounds__(256) void k_pair(const float* __restrict__ z1, const float* __restrict__ x,
                                              float* __restrict__ zp,
                                              const float* __restrict__ A1, const float* __restrict__ ab1,
                                              const float* __restrict__ A2, const float* __restrict__ ab2,
                                              const float* __restrict__ emb, int total) {
    __shared__ float eA1[64 * ADJ_HID];
    __shared__ float a0[ADJ_HID], a1[ADJ_HID], a2[ADJ_HID];
    int tid = threadIdx.x;
    if (tid < ADJ_HID) { a0[tid] = A1[tid]; a1[tid] = A1[ADJ_HID + tid]; a2[tid] = A2[tid]; }
    for (int idx = tid; idx < 64 * ADJ_HID; idx += 256) {
        int c = idx / ADJ_HID, h = idx - c * ADJ_HID;
        float s = ab1[h];
        #pragma unroll
        for (int j = 0; j < EMB_DIM; j++) s = fmaf(emb[c * EMB_DIM + j], A1[(2 + j) * ADJ_HID + h], s);
        eA1[idx] = s;
    }
    __syncthreads();
    int i = blockIdx.x * 256 + tid;
    if (i >= total) return;
    float v0 = z1[i], v1 = x[i];
    int c = i & 63;
    float out = ab2[0];
    #pragma unroll
    for (int h = 0; h < ADJ_HID; h++) {
        float t = fmaf(v0, a0[h], fmaf(v1, a1[h], eA1[c * ADJ_HID + h]));
        t = fmaxf(t, 0.f);
        out = fmaf(t, a2[h], out);
    }
    zp[i] = out * 0.5f;
}

// ---------------- node MLP: concat([zp,x]) @ W1 -> relu -> @ W2 ----------------

__global__ __launch_bounds__(256) void k_mlp(const float* __restrict__ zp, const float* __restrict__ x,
                                             const float* __restrict__ W1, const float* __restrict__ b1,
                                             const float* __restrict__ W2, const float* __restrict__ b2,
                                             float* __restrict__ g0, int n) {
    __shared__ float in128[4][128];
    __shared__ float hid[4][64];
    int tid  = threadIdx.x;
    int wg   = tid >> 6;
    int lane = tid & 63;
    int node = blockIdx.x * 4 + wg;
    if (node < n) {
        in128[wg][lane]      = zp[(size_t)node * 64 + lane];
        in128[wg][64 + lane] = x[(size_t)node * 64 + lane];
    }
    __syncthreads();
    if (node < n) {
        float acc = b1[lane];
        #pragma unroll 8
        for (int r = 0; r < 128; r++) acc = fmaf(in128[wg][r], W1[r * 64 + lane], acc);
        hid[wg][lane] = fmaxf(acc, 0.f);
    }
    __syncthreads();
    if (node < n && lane < 16) {
        float acc = b2[lane];
        #pragma unroll 8
        for (int h = 0; h < 64; h++) acc = fmaf(hid[wg][h], W2[h * 16 + lane], acc);
        g0[(size_t)node * 16 + lane] = acc;
    }
}

// ---------------- launch ----------------

extern "C" void kernel_launch(void* const* d_in, const int* in_sizes, int n_in,
                              void* d_out, int out_size, void* d_ws, size_t ws_size,
                              hipStream_t stream) {
    const float* x   = (const float*)d_in[0];
    const int*   src = (const int*)d_in[1];
    const int*   dst = (const int*)d_in[2];
    const float* W1  = (const float*)d_in[3];
    const float* b1  = (const float*)d_in[4];
    const float* W2  = (const float*)d_in[5];
    const float* b2  = (const float*)d_in[6];
    const float* A1  = (const float*)d_in[7];
    const float* ab1 = (const float*)d_in[8];
    const float* A2  = (const float*)d_in[9];
    const float* ab2 = (const float*)d_in[10];
    const float* emb = (const float*)d_in[11];

    int n = in_sizes[0] / FEATS;   // 50000
    int e = in_sizes[1];           // 800000

    char* ws = (char*)d_ws;
    size_t off = 0;
    auto alloc = [&](size_t bytes) {
        void* p = ws + off;
        off += bytes;
        off = (off + 255) & ~(size_t)255;
        return p;
    };

    int*   deg    = (int*)  alloc((size_t)n * 4);
    float* invs   = (float*)alloc((size_t)n * 4);
    int*   rowptr = (int*)  alloc((size_t)(n + 1) * 4);
    int*   cnt    = (int*)  alloc((size_t)n * 4);
    int*   bsum   = (int*)  alloc(1024);
    int*   ssrc   = (int*)  alloc((size_t)e * 4);
    float* snorm  = (float*)alloc((size_t)e * 4);
    float* zA     = (float*)alloc((size_t)n * 64 * 4);
    float* zB     = (float*)alloc((size_t)n * 64 * 4);
    // g buffers overlay nothing; small
    float* g0     = (float*)alloc((size_t)n * 16 * 4);
    float* g1     = (float*)alloc((size_t)n * 16 * 4);
    float* g2     = (float*)alloc((size_t)n * 16 * 4);

    hipMemsetAsync(deg, 0, (size_t)n * 4, stream);
    hipMemsetAsync(cnt, 0, (size_t)n * 4, stream);

    int eb = (e + 255) / 256;
    int nb = (n + 255) / 256;

    k_deg    <<<eb, 256, 0, stream>>>(dst, deg, e);
    k_invs   <<<nb, 256, 0, stream>>>(deg, invs, n);
    k_scan1  <<<nb, 256, 0, stream>>>(deg, rowptr, bsum, n);
    k_scan2  <<<1, 256, 0, stream>>>(bsum, nb);
    k_scan3  <<<(n + 256) / 256, 256, 0, stream>>>(rowptr, bsum, n, e);
    k_scatter<<<eb, 256, 0, stream>>>(src, dst, invs, rowptr, cnt, ssrc, snorm, e);

    // diffusion over features (10 iters), ping-pong x -> zA -> zB -> ...
    const float* zin = x;
    float* zout = zA;
    for (int it = 0; it < 10; ++it) {
        k_conv64<<<((size_t)n * 64 + 255) / 256, 256, 0, stream>>>(zin, x, zout, rowptr, ssrc, snorm, n);
        zin  = zout;
        zout = (zout == zA) ? zB : zA;
    }
    const float* z1 = zin;                 // zB after 10 iters
    float* zp = (z1 == zA) ? zB : zA;      // free buffer

    k_pair<<<((size_t)n * 64 + 255) / 256, 256, 0, stream>>>(z1, x, zp, A1, ab1, A2, ab2, emb, n * 64);
    k_mlp <<<(n + 3) / 4, 256, 0, stream>>>(zp, x, W1, b1, W2, b2, g0, n);

    // diffusion over logits (10 iters)
    const float* gin = g0;
    float* gout = g1;
    for (int it = 0; it < 10; ++it) {
        float* out = (it == 9) ? (float*)d_out : gout;
        k_conv16<<<((size_t)n * 16 + 255) / 256, 256, 0, stream>>>(gin, g0, out, rowptr, ssrc, snorm, n);
        gin  = out;
        gout = (gout == g1) ? g2 : g1;
    }
}

// Round 2
// 783.363 us; speedup vs baseline: 1.2440x; 1.2440x over previous
//
#include <hip/hip_runtime.h>

#define FEATS    64
#define CLASSES  16
#define EMB_DIM  7
#define ADJ_HID  11
#define DIFF     0.9f

// ---------------- graph preprocessing ----------------

__global__ __launch_bounds__(256) void k_deg(const int* __restrict__ dst, int* __restrict__ deg, int e) {
    int i = blockIdx.x * 256 + threadIdx.x;
    if (i < e) atomicAdd(&deg[dst[i]], 1);
}

__global__ __launch_bounds__(256) void k_invs(const int* __restrict__ deg, float* __restrict__ invs, int n) {
    int i = blockIdx.x * 256 + threadIdx.x;
    if (i < n) { int d = deg[i]; invs[i] = d > 0 ? rsqrtf((float)d) : 0.f; }
}

__global__ __launch_bounds__(256) void k_scan1(const int* __restrict__ deg, int* __restrict__ rowptr,
                                               int* __restrict__ bsum, int n) {
    __shared__ int s[256];
    int tid = threadIdx.x;
    int i = blockIdx.x * 256 + tid;
    int v = (i < n) ? deg[i] : 0;
    s[tid] = v; __syncthreads();
    for (int ofs = 1; ofs < 256; ofs <<= 1) {
        int t = (tid >= ofs) ? s[tid - ofs] : 0;
        __syncthreads(); s[tid] += t; __syncthreads();
    }
    if (i < n) rowptr[i] = s[tid] - v;              // exclusive within block
    if (tid == 255) bsum[blockIdx.x] = s[255];      // block total
}

__global__ __launch_bounds__(256) void k_scan2(int* __restrict__ bsum, int nb) {
    __shared__ int s[256];
    int tid = threadIdx.x;
    int v = (tid < nb) ? bsum[tid] : 0;
    s[tid] = v; __syncthreads();
    for (int ofs = 1; ofs < 256; ofs <<= 1) {
        int t = (tid >= ofs) ? s[tid - ofs] : 0;
        __syncthreads(); s[tid] += t; __syncthreads();
    }
    if (tid < nb) bsum[tid] = s[tid] - v;           // exclusive block offsets
}

__global__ __launch_bounds__(256) void k_scan3(int* __restrict__ rowptr, const int* __restrict__ bsum,
                                               int n, int e) {
    int i = blockIdx.x * 256 + threadIdx.x;
    if (i < n) rowptr[i] += bsum[i >> 8];
    if (i == n) rowptr[n] = e;
}

__global__ __launch_bounds__(256) void k_scatter(const int* __restrict__ src, const int* __restrict__ dst,
                                                 const float* __restrict__ invs, const int* __restrict__ rowptr,
                                                 int* __restrict__ cnt, int2* __restrict__ edge, int e) {
    int i = blockIdx.x * 256 + threadIdx.x;
    if (i >= e) return;
    int d = dst[i], sv = src[i];
    int pos = rowptr[d] + atomicAdd(&cnt[d], 1);
    edge[pos] = make_int2(sv, __float_as_int(invs[sv] * invs[d]));
}

// ---------------- diffusion convs (pull, CSR, 4-deep gather pipeline) ----------------

__global__ __launch_bounds__(256) void k_conv64(const float* __restrict__ zin, const float* __restrict__ h0,
                                                float* __restrict__ zout, const int* __restrict__ rowptr,
                                                const int2* __restrict__ edge, int n) {
    int g = blockIdx.x * 256 + threadIdx.x;
    int node = g >> 6;
    if (node >= n) return;
    int f = g & 63;
    int e0 = rowptr[node], e1 = rowptr[node + 1];
    float a0 = 0.f, a1 = 0.f, a2 = 0.f, a3 = 0.f;
    int e = e0;
    for (; e + 3 < e1; e += 4) {
        int2 p0 = edge[e], p1 = edge[e + 1], p2 = edge[e + 2], p3 = edge[e + 3];
        a0 = fmaf(__int_as_float(p0.y), zin[(size_t)p0.x * 64 + f], a0);
        a1 = fmaf(__int_as_float(p1.y), zin[(size_t)p1.x * 64 + f], a1);
        a2 = fmaf(__int_as_float(p2.y), zin[(size_t)p2.x * 64 + f], a2);
        a3 = fmaf(__int_as_float(p3.y), zin[(size_t)p3.x * 64 + f], a3);
    }
    for (; e < e1; ++e) {
        int2 p = edge[e];
        a0 = fmaf(__int_as_float(p.y), zin[(size_t)p.x * 64 + f], a0);
    }
    zout[(size_t)node * 64 + f] = ((a0 + a1) + (a2 + a3)) * DIFF
                                  + (1.f - DIFF) * h0[(size_t)node * 64 + f];
}

__global__ __launch_bounds__(256) void k_conv16(const float* __restrict__ zin, const float* __restrict__ g0,
                                                float* __restrict__ zout, const int* __restrict__ rowptr,
                                                const int2* __restrict__ edge, int n) {
    int g = blockIdx.x * 256 + threadIdx.x;
    int node = g >> 4;
    if (node >= n) return;
    int f = g & 15;
    int e0 = rowptr[node], e1 = rowptr[node + 1];
    float a0 = 0.f, a1 = 0.f, a2 = 0.f, a3 = 0.f;
    int e = e0;
    for (; e + 3 < e1; e += 4) {
        int2 p0 = edge[e], p1 = edge[e + 1], p2 = edge[e + 2], p3 = edge[e + 3];
        a0 = fmaf(__int_as_float(p0.y), zin[(size_t)p0.x * 16 + f], a0);
        a1 = fmaf(__int_as_float(p1.y), zin[(size_t)p1.x * 16 + f], a1);
        a2 = fmaf(__int_as_float(p2.y), zin[(size_t)p2.x * 16 + f], a2);
        a3 = fmaf(__int_as_float(p3.y), zin[(size_t)p3.x * 16 + f], a3);
    }
    for (; e < e1; ++e) {
        int2 p = edge[e];
        a0 = fmaf(__int_as_float(p.y), zin[(size_t)p.x * 16 + f], a0);
    }
    zout[(size_t)node * 16 + f] = ((a0 + a1) + (a2 + a3)) * DIFF
                                  + (1.f - DIFF) * g0[(size_t)node * 16 + f];
}

// ---------------- fused pair-MLP + node-MLP ----------------
// Per block: 32 nodes. Phases:
//  A: stage W1 (32KB), W2, eA1 table into LDS
//  B: pair MLP elementwise -> in_s[32][128]  (zp | x)
//  C: GEMM1 [32,128]@[128,64] relu -> hid (8 acc/thread register blocking)
//  D: GEMM2 [32,64]@[64,16] -> g0

__global__ __launch_bounds__(256) void k_pairmlp(const float* __restrict__ z1, const float* __restrict__ x,
                                                 const float* __restrict__ W1, const float* __restrict__ b1,
                                                 const float* __restrict__ W2, const float* __restrict__ b2,
                                                 const float* __restrict__ A1, const float* __restrict__ ab1,
                                                 const float* __restrict__ A2, const float* __restrict__ ab2,
                                                 const float* __restrict__ emb,
                                                 float* __restrict__ g0, int n) {
    __shared__ float W1s[128 * 64];          // 32 KB, [r][h]
    __shared__ float W2s[64 * 16];           // 4 KB,  [h][c]
    __shared__ float in_s[32][128];          // 16 KB
    __shared__ float hid[32 * 65];           // 8.3 KB (padded rows)
    __shared__ float eA1[64 * ADJ_HID];      // 2.8 KB
    __shared__ float a0s[ADJ_HID], a1s[ADJ_HID], a2s[ADJ_HID];
    __shared__ float ab2s;

    int tid  = threadIdx.x;
    int base = blockIdx.x * 32;

    // ---- phase A ----
    #pragma unroll
    for (int k = 0; k < 32; ++k) W1s[tid + k * 256] = W1[tid + k * 256];
    #pragma unroll
    for (int k = 0; k < 4; ++k)  W2s[tid + k * 256] = W2[tid + k * 256];
    if (tid < ADJ_HID) { a0s[tid] = A1[tid]; a1s[tid] = A1[ADJ_HID + tid]; a2s[tid] = A2[tid]; }
    if (tid == 0) ab2s = ab2[0];
    for (int idx = tid; idx < 64 * ADJ_HID; idx += 256) {
        int c = idx / ADJ_HID, h = idx - c * ADJ_HID;
        float s = ab1[h];
        #pragma unroll
        for (int j = 0; j < EMB_DIM; j++) s = fmaf(emb[c * EMB_DIM + j], A1[(2 + j) * ADJ_HID + h], s);
        eA1[idx] = s;
    }
    __syncthreads();

    // ---- phase B: pair MLP ----
    #pragma unroll
    for (int k = 0; k < 8; ++k) {
        int idx = tid + k * 256;             // 0..2047
        int nl = idx >> 6, c = idx & 63;
        int node = base + nl; if (node > n - 1) node = n - 1;
        float zv = z1[(size_t)node * 64 + c];
        float xv = x[(size_t)node * 64 + c];
        float out = ab2s;
        #pragma unroll
        for (int h = 0; h < ADJ_HID; h++) {
            float t = fmaf(zv, a0s[h], fmaf(xv, a1s[h], eA1[c * ADJ_HID + h]));
            t = fmaxf(t, 0.f);
            out = fmaf(t, a2s[h], out);
        }
        in_s[nl][c]      = out * 0.5f;
        in_s[nl][64 + c] = xv;
    }
    __syncthreads();

    // ---- phase C: GEMM1, wave w handles nodes w*8..w*8+7, lane = hidden unit ----
    {
        int lane = tid & 63, wv = tid >> 6;
        int nb0 = wv * 8;
        float bv = b1[lane];
        float acc[8];
        #pragma unroll
        for (int j = 0; j < 8; ++j) acc[j] = bv;
        #pragma unroll 8
        for (int rb = 0; rb < 128; rb += 4) {
            float w0 = W1s[(rb    ) * 64 + lane];
            float w1 = W1s[(rb + 1) * 64 + lane];
            float w2 = W1s[(rb + 2) * 64 + lane];
            float w3 = W1s[(rb + 3) * 64 + lane];
            #pragma unroll
            for (int j = 0; j < 8; ++j) {
                float4 iv = *(const float4*)&in_s[nb0 + j][rb];
                acc[j] = fmaf(iv.w, w3, fmaf(iv.z, w2, fmaf(iv.y, w1, fmaf(iv.x, w0, acc[j]))));
            }
        }
        #pragma unroll
        for (int j = 0; j < 8; ++j) hid[(nb0 + j) * 65 + lane] = fmaxf(acc[j], 0.f);
    }
    __syncthreads();

    // ---- phase D: GEMM2, thread = (node pair, class) ----
    {
        int c  = tid & 15;
        int nl = tid >> 4;                   // 0..15, handles nl and nl+16
        float ac0 = b2[c], ac1 = ac0;
        #pragma unroll
        for (int h = 0; h < 64; ++h) {
            float w = W2s[h * 16 + c];
            ac0 = fmaf(hid[nl * 65 + h],        w, ac0);
            ac1 = fmaf(hid[(nl + 16) * 65 + h], w, ac1);
        }
        int n0 = base + nl, n1 = base + nl + 16;
        if (n0 < n) g0[(size_t)n0 * 16 + c] = ac0;
        if (n1 < n) g0[(size_t)n1 * 16 + c] = ac1;
    }
}

// ---------------- launch ----------------

extern "C" void kernel_launch(void* const* d_in, const int* in_sizes, int n_in,
                              void* d_out, int out_size, void* d_ws, size_t ws_size,
                              hipStream_t stream) {
    const float* x   = (const float*)d_in[0];
    const int*   src = (const int*)d_in[1];
    const int*   dst = (const int*)d_in[2];
    const float* W1  = (const float*)d_in[3];
    const float* b1  = (const float*)d_in[4];
    const float* W2  = (const float*)d_in[5];
    const float* b2  = (const float*)d_in[6];
    const float* A1  = (const float*)d_in[7];
    const float* ab1 = (const float*)d_in[8];
    const float* A2  = (const float*)d_in[9];
    const float* ab2 = (const float*)d_in[10];
    const float* emb = (const float*)d_in[11];

    int n = in_sizes[0] / FEATS;   // 50000
    int e = in_sizes[1];           // 800000

    char* ws = (char*)d_ws;
    size_t off = 0;
    auto alloc = [&](size_t bytes) {
        void* p = ws + off;
        off += bytes;
        off = (off + 255) & ~(size_t)255;
        return p;
    };

    int*   deg    = (int*)  alloc((size_t)n * 4);
    float* invs   = (float*)alloc((size_t)n * 4);
    int*   rowptr = (int*)  alloc((size_t)(n + 1) * 4);
    int*   cnt    = (int*)  alloc((size_t)n * 4);
    int*   bsum   = (int*)  alloc(1024);
    int2*  edge   = (int2*) alloc((size_t)e * 8);
    float* zA     = (float*)alloc((size_t)n * 64 * 4);
    float* zB     = (float*)alloc((size_t)n * 64 * 4);
    float* g0     = (float*)alloc((size_t)n * 16 * 4);
    float* g1     = (float*)alloc((size_t)n * 16 * 4);
    float* g2     = (float*)alloc((size_t)n * 16 * 4);

    hipMemsetAsync(deg, 0, (size_t)n * 4, stream);
    hipMemsetAsync(cnt, 0, (size_t)n * 4, stream);

    int eb = (e + 255) / 256;
    int nb = (n + 255) / 256;

    k_deg    <<<eb, 256, 0, stream>>>(dst, deg, e);
    k_invs   <<<nb, 256, 0, stream>>>(deg, invs, n);
    k_scan1  <<<nb, 256, 0, stream>>>(deg, rowptr, bsum, n);
    k_scan2  <<<1, 256, 0, stream>>>(bsum, nb);
    k_scan3  <<<(n + 256) / 256, 256, 0, stream>>>(rowptr, bsum, n, e);
    k_scatter<<<eb, 256, 0, stream>>>(src, dst, invs, rowptr, cnt, edge, e);

    // diffusion over features (10 iters), ping-pong x -> zA -> zB -> ...
    const float* zin = x;
    float* zout = zA;
    for (int it = 0; it < 10; ++it) {
        k_conv64<<<((size_t)n * 64 + 255) / 256, 256, 0, stream>>>(zin, x, zout, rowptr, edge, n);
        zin  = zout;
        zout = (zout == zA) ? zB : zA;
    }
    const float* z1 = zin;

    k_pairmlp<<<(n + 31) / 32, 256, 0, stream>>>(z1, x, W1, b1, W2, b2,
                                                 A1, ab1, A2, ab2, emb, g0, n);

    // diffusion over logits (10 iters)
    const float* gin = g0;
    float* gout = g1;
    for (int it = 0; it < 10; ++it) {
        float* out = (it == 9) ? (float*)d_out : gout;
        k_conv16<<<((size_t)n * 16 + 255) / 256, 256, 0, stream>>>(gin, g0, out, rowptr, edge, n);
        gin  = out;
        gout = (gout == g1) ? g2 : g1;
    }
}

// Round 4
// 739.871 us; speedup vs baseline: 1.3172x; 1.0588x over previous
//
#include <hip/hip_runtime.h>

#define FEATS    64
#define CLASSES  16
#define EMB_DIM  7
#define ADJ_HID  11
#define DIFF     0.9f

__device__ inline float4 shfl_xor4(float4 v, int mask) {
    float4 r;
    r.x = __shfl_xor(v.x, mask);
    r.y = __shfl_xor(v.y, mask);
    r.z = __shfl_xor(v.z, mask);
    r.w = __shfl_xor(v.w, mask);
    return r;
}

// ---------------- graph preprocessing ----------------

__global__ __launch_bounds__(256) void k_deg(const int* __restrict__ dst, int* __restrict__ deg, int e) {
    int i = blockIdx.x * 256 + threadIdx.x;
    if (i < e) atomicAdd(&deg[dst[i]], 1);
}

__global__ __launch_bounds__(256) void k_invs(const int* __restrict__ deg, float* __restrict__ invs, int n) {
    int i = blockIdx.x * 256 + threadIdx.x;
    if (i < n) { int d = deg[i]; invs[i] = d > 0 ? rsqrtf((float)d) : 0.f; }
}

__global__ __launch_bounds__(256) void k_scan1(const int* __restrict__ deg, int* __restrict__ rowptr,
                                               int* __restrict__ bsum, int n) {
    __shared__ int s[256];
    int tid = threadIdx.x;
    int i = blockIdx.x * 256 + tid;
    int v = (i < n) ? deg[i] : 0;
    s[tid] = v; __syncthreads();
    for (int ofs = 1; ofs < 256; ofs <<= 1) {
        int t = (tid >= ofs) ? s[tid - ofs] : 0;
        __syncthreads(); s[tid] += t; __syncthreads();
    }
    if (i < n) rowptr[i] = s[tid] - v;
    if (tid == 255) bsum[blockIdx.x] = s[255];
}

__global__ __launch_bounds__(256) void k_scan2(int* __restrict__ bsum, int nb) {
    __shared__ int s[256];
    int tid = threadIdx.x;
    int v = (tid < nb) ? bsum[tid] : 0;
    s[tid] = v; __syncthreads();
    for (int ofs = 1; ofs < 256; ofs <<= 1) {
        int t = (tid >= ofs) ? s[tid - ofs] : 0;
        __syncthreads(); s[tid] += t; __syncthreads();
    }
    if (tid < nb) bsum[tid] = s[tid] - v;
}

__global__ __launch_bounds__(256) void k_scan3(int* __restrict__ rowptr, const int* __restrict__ bsum,
                                               int n, int e) {
    int i = blockIdx.x * 256 + threadIdx.x;
    if (i < n) rowptr[i] += bsum[i >> 8];
    if (i == n) rowptr[n] = e;
}

__global__ __launch_bounds__(256) void k_scatter(const int* __restrict__ src, const int* __restrict__ dst,
                                                 const float* __restrict__ invs, const int* __restrict__ rowptr,
                                                 int* __restrict__ cnt, int2* __restrict__ edge, int e) {
    int i = blockIdx.x * 256 + threadIdx.x;
    if (i >= e) return;
    int d = dst[i], sv = src[i];
    int pos = rowptr[d] + atomicAdd(&cnt[d], 1);
    edge[pos] = make_int2(sv, __float_as_int(invs[sv] * invs[d]));
}

// ---------------- conv64: 1 wave/node, 16 lanes/edge (float4), 16 edges in flight ----------------

__global__ __launch_bounds__(256) void k_conv64(const float4* __restrict__ zin4, const float4* __restrict__ h04,
                                                float4* __restrict__ zout4, const int* __restrict__ rowptr,
                                                const int2* __restrict__ edge, int n) {
    int wid = (blockIdx.x * 256 + threadIdx.x) >> 6;   // node
    if (wid >= n) return;
    int lane = threadIdx.x & 63;
    int g = lane >> 4, c = lane & 15;
    int e0 = rowptr[wid], e1 = rowptr[wid + 1];
    float4 acc; acc.x = acc.y = acc.z = acc.w = 0.f;
    for (int e = e0; e < e1; e += 16) {
        #pragma unroll
        for (int k = 0; k < 4; ++k) {
            int idx = e + k * 4 + g;
            bool ok = idx < e1;
            int2 p = edge[ok ? idx : e0];
            float w = ok ? __int_as_float(p.y) : 0.f;
            float4 v = zin4[(size_t)p.x * 16 + c];
            acc.x = fmaf(w, v.x, acc.x);
            acc.y = fmaf(w, v.y, acc.y);
            acc.z = fmaf(w, v.z, acc.z);
            acc.w = fmaf(w, v.w, acc.w);
        }
    }
    float4 t = shfl_xor4(acc, 16);
    acc.x += t.x; acc.y += t.y; acc.z += t.z; acc.w += t.w;
    t = shfl_xor4(acc, 32);
    acc.x += t.x; acc.y += t.y; acc.z += t.z; acc.w += t.w;
    if (lane < 16) {
        float4 h = h04[(size_t)wid * 16 + lane];
        float4 o;
        o.x = acc.x * DIFF + (1.f - DIFF) * h.x;
        o.y = acc.y * DIFF + (1.f - DIFF) * h.y;
        o.z = acc.z * DIFF + (1.f - DIFF) * h.z;
        o.w = acc.w * DIFF + (1.f - DIFF) * h.w;
        zout4[(size_t)wid * 16 + lane] = o;
    }
}

// ---------------- conv16: 1 wave/node, 4 lanes/edge (float4), 32 edges in flight ----------------

__global__ __launch_bounds__(256) void k_conv16(const float4* __restrict__ zin4, const float4* __restrict__ g04,
                                                float4* __restrict__ zout4, const int* __restrict__ rowptr,
                                                const int2* __restrict__ edge, int n) {
    int wid = (blockIdx.x * 256 + threadIdx.x) >> 6;   // node
    if (wid >= n) return;
    int lane = threadIdx.x & 63;
    int g = lane >> 2, c = lane & 3;
    int e0 = rowptr[wid], e1 = rowptr[wid + 1];
    float4 acc; acc.x = acc.y = acc.z = acc.w = 0.f;
    for (int e = e0; e < e1; e += 32) {
        #pragma unroll
        for (int k = 0; k < 2; ++k) {
            int idx = e + k * 16 + g;
            bool ok = idx < e1;
            int2 p = edge[ok ? idx : e0];
            float w = ok ? __int_as_float(p.y) : 0.f;
            float4 v = zin4[(size_t)p.x * 4 + c];
            acc.x = fmaf(w, v.x, acc.x);
            acc.y = fmaf(w, v.y, acc.y);
            acc.z = fmaf(w, v.z, acc.z);
            acc.w = fmaf(w, v.w, acc.w);
        }
    }
    float4 t = shfl_xor4(acc, 4);
    acc.x += t.x; acc.y += t.y; acc.z += t.z; acc.w += t.w;
    t = shfl_xor4(acc, 8);
    acc.x += t.x; acc.y += t.y; acc.z += t.z; acc.w += t.w;
    t = shfl_xor4(acc, 16);
    acc.x += t.x; acc.y += t.y; acc.z += t.z; acc.w += t.w;
    t = shfl_xor4(acc, 32);
    acc.x += t.x; acc.y += t.y; acc.z += t.z; acc.w += t.w;
    if (lane < 4) {
        float4 h = g04[(size_t)wid * 4 + lane];
        float4 o;
        o.x = acc.x * DIFF + (1.f - DIFF) * h.x;
        o.y = acc.y * DIFF + (1.f - DIFF) * h.y;
        o.z = acc.z * DIFF + (1.f - DIFF) * h.z;
        o.w = acc.w * DIFF + (1.f - DIFF) * h.w;
        zout4[(size_t)wid * 4 + lane] = o;
    }
}

// ---------------- fused pair-MLP + node-MLP (W1 read from global/L2; LDS ~31.5 KB) ----------------

__global__ __launch_bounds__(256) void k_pairmlp(const float* __restrict__ z1, const float* __restrict__ x,
                                                 const float* __restrict__ W1, const float* __restrict__ b1,
                                                 const float* __restrict__ W2, const float* __restrict__ b2,
                                                 const float* __restrict__ A1, const float* __restrict__ ab1,
                                                 const float* __restrict__ A2, const float* __restrict__ ab2,
                                                 const float* __restrict__ emb,
                                                 float* __restrict__ g0, int n) {
    __shared__ float W2s[64 * 16];           // 4 KB
    __shared__ float in_s[32][128];          // 16 KB
    __shared__ float hid[32 * 65];           // 8.3 KB
    __shared__ float eA1[64 * ADJ_HID];      // 2.8 KB
    __shared__ float a0s[ADJ_HID], a1s[ADJ_HID], a2s[ADJ_HID];
    __shared__ float ab2s;

    int tid  = threadIdx.x;
    int base = blockIdx.x * 32;

    // ---- phase A: small tables ----
    #pragma unroll
    for (int k = 0; k < 4; ++k)  W2s[tid + k * 256] = W2[tid + k * 256];
    if (tid < ADJ_HID) { a0s[tid] = A1[tid]; a1s[tid] = A1[ADJ_HID + tid]; a2s[tid] = A2[tid]; }
    if (tid == 0) ab2s = ab2[0];
    for (int idx = tid; idx < 64 * ADJ_HID; idx += 256) {
        int c = idx / ADJ_HID, h = idx - c * ADJ_HID;
        float s = ab1[h];
        #pragma unroll
        for (int j = 0; j < EMB_DIM; j++) s = fmaf(emb[c * EMB_DIM + j], A1[(2 + j) * ADJ_HID + h], s);
        eA1[idx] = s;
    }
    __syncthreads();

    // ---- phase B: pair MLP ----
    #pragma unroll
    for (int k = 0; k < 8; ++k) {
        int idx = tid + k * 256;             // 0..2047
        int nl = idx >> 6, c = idx & 63;
        int node = base + nl; if (node > n - 1) node = n - 1;
        float zv = z1[(size_t)node * 64 + c];
        float xv = x[(size_t)node * 64 + c];
        float out = ab2s;
        #pragma unroll
        for (int h = 0; h < ADJ_HID; h++) {
            float t = fmaf(zv, a0s[h], fmaf(xv, a1s[h], eA1[c * ADJ_HID + h]));
            t = fmaxf(t, 0.f);
            out = fmaf(t, a2s[h], out);
        }
        in_s[nl][c]      = out * 0.5f;
        in_s[nl][64 + c] = xv;
    }
    __syncthreads();

    // ---- phase C: GEMM1, W1 streamed from global (L2-resident) ----
    {
        int lane = tid & 63, wv = tid >> 6;
        int nb0 = wv * 8;
        float bv = b1[lane];
        float acc[8];
        #pragma unroll
        for (int j = 0; j < 8; ++j) acc[j] = bv;
        #pragma unroll 8
        for (int rb = 0; rb < 128; rb += 4) {
            float w0 = W1[(rb    ) * 64 + lane];
            float w1 = W1[(rb + 1) * 64 + lane];
            float w2 = W1[(rb + 2) * 64 + lane];
            float w3 = W1[(rb + 3) * 64 + lane];
            #pragma unroll
            for (int j = 0; j < 8; ++j) {
                float4 iv = *(const float4*)&in_s[nb0 + j][rb];
                acc[j] = fmaf(iv.w, w3, fmaf(iv.z, w2, fmaf(iv.y, w1, fmaf(iv.x, w0, acc[j]))));
            }
        }
        #pragma unroll
        for (int j = 0; j < 8; ++j) hid[(nb0 + j) * 65 + lane] = fmaxf(acc[j], 0.f);
    }
    __syncthreads();

    // ---- phase D: GEMM2 ----
    {
        int c  = tid & 15;
        int nl = tid >> 4;
        float ac0 = b2[c], ac1 = ac0;
        #pragma unroll
        for (int h = 0; h < 64; ++h) {
            float w = W2s[h * 16 + c];
            ac0 = fmaf(hid[nl * 65 + h],        w, ac0);
            ac1 = fmaf(hid[(nl + 16) * 65 + h], w, ac1);
        }
        int n0 = base + nl, n1 = base + nl + 16;
        if (n0 < n) g0[(size_t)n0 * 16 + c] = ac0;
        if (n1 < n) g0[(size_t)n1 * 16 + c] = ac1;
    }
}

// ---------------- launch ----------------

extern "C" void kernel_launch(void* const* d_in, const int* in_sizes, int n_in,
                              void* d_out, int out_size, void* d_ws, size_t ws_size,
                              hipStream_t stream) {
    const float* x   = (const float*)d_in[0];
    const int*   src = (const int*)d_in[1];
    const int*   dst = (const int*)d_in[2];
    const float* W1  = (const float*)d_in[3];
    const float* b1  = (const float*)d_in[4];
    const float* W2  = (const float*)d_in[5];
    const float* b2  = (const float*)d_in[6];
    const float* A1  = (const float*)d_in[7];
    const float* ab1 = (const float*)d_in[8];
    const float* A2  = (const float*)d_in[9];
    const float* ab2 = (const float*)d_in[10];
    const float* emb = (const float*)d_in[11];

    int n = in_sizes[0] / FEATS;   // 50000
    int e = in_sizes[1];           // 800000

    char* ws = (char*)d_ws;
    size_t off = 0;
    auto alloc = [&](size_t bytes) {
        void* p = ws + off;
        off += bytes;
        off = (off + 255) & ~(size_t)255;
        return p;
    };

    int*   deg    = (int*)  alloc((size_t)n * 4);
    float* invs   = (float*)alloc((size_t)n * 4);
    int*   rowptr = (int*)  alloc((size_t)(n + 1) * 4);
    int*   cnt    = (int*)  alloc((size_t)n * 4);
    int*   bsum   = (int*)  alloc(1024);
    int2*  edge   = (int2*) alloc((size_t)e * 8 + 256);
    float* zA     = (float*)alloc((size_t)n * 64 * 4);
    float* zB     = (float*)alloc((size_t)n * 64 * 4);
    float* g0     = (float*)alloc((size_t)n * 16 * 4);
    float* g1     = (float*)alloc((size_t)n * 16 * 4);
    float* g2     = (float*)alloc((size_t)n * 16 * 4);

    hipMemsetAsync(deg, 0, (size_t)n * 4, stream);
    hipMemsetAsync(cnt, 0, (size_t)n * 4, stream);

    int eb = (e + 255) / 256;
    int nb = (n + 255) / 256;

    k_deg    <<<eb, 256, 0, stream>>>(dst, deg, e);
    k_invs   <<<nb, 256, 0, stream>>>(deg, invs, n);
    k_scan1  <<<nb, 256, 0, stream>>>(deg, rowptr, bsum, n);
    k_scan2  <<<1, 256, 0, stream>>>(bsum, nb);
    k_scan3  <<<(n + 256) / 256, 256, 0, stream>>>(rowptr, bsum, n, e);
    k_scatter<<<eb, 256, 0, stream>>>(src, dst, invs, rowptr, cnt, edge, e);

    int nwb = (n + 3) / 4;   // 4 waves (nodes) per 256-thread block

    // diffusion over features (10 iters)
    const float* zin = x;
    float* zout = zA;
    for (int it = 0; it < 10; ++it) {
        k_conv64<<<nwb, 256, 0, stream>>>((const float4*)zin, (const float4*)x, (float4*)zout,
                                          rowptr, edge, n);
        zin  = zout;
        zout = (zout == zA) ? zB : zA;
    }
    const float* z1 = zin;

    k_pairmlp<<<(n + 31) / 32, 256, 0, stream>>>(z1, x, W1, b1, W2, b2,
                                                 A1, ab1, A2, ab2, emb, g0, n);

    // diffusion over logits (10 iters)
    const float* gin = g0;
    float* gout = g1;
    for (int it = 0; it < 10; ++it) {
        float* out = (it == 9) ? (float*)d_out : gout;
        k_conv16<<<nwb, 256, 0, stream>>>((const float4*)gin, (const float4*)g0, (float4*)out,
                                          rowptr, edge, n);
        gin  = out;
        gout = (gout == g1) ? g2 : g1;
    }
}

// Round 5
// 706.139 us; speedup vs baseline: 1.3801x; 1.0478x over previous
//
#include <hip/hip_runtime.h>

#define FEATS    64
#define CLASSES  16
#define EMB_DIM  7
#define ADJ_HID  11
#define DIFF     0.9f

__device__ inline float bf2f(unsigned short u) {
    return __uint_as_float(((unsigned int)u) << 16);
}
__device__ inline unsigned short f2bf(float f) {
    unsigned int u = __float_as_uint(f);
    return (unsigned short)((u + 0x7FFFu + ((u >> 16) & 1u)) >> 16);
}

// ---------------- graph preprocessing ----------------

__global__ __launch_bounds__(256) void k_deg(const int* __restrict__ dst, int* __restrict__ deg, int e) {
    int i = blockIdx.x * 256 + threadIdx.x;
    if (i < e) atomicAdd(&deg[dst[i]], 1);
}

__global__ __launch_bounds__(256) void k_invs(const int* __restrict__ deg, float* __restrict__ invs, int n) {
    int i = blockIdx.x * 256 + threadIdx.x;
    if (i < n) { int d = deg[i]; invs[i] = d > 0 ? rsqrtf((float)d) : 0.f; }
}

__global__ __launch_bounds__(256) void k_scan1(const int* __restrict__ deg, int* __restrict__ rowptr,
                                               int* __restrict__ bsum, int n) {
    __shared__ int s[256];
    int tid = threadIdx.x;
    int i = blockIdx.x * 256 + tid;
    int v = (i < n) ? deg[i] : 0;
    s[tid] = v; __syncthreads();
    for (int ofs = 1; ofs < 256; ofs <<= 1) {
        int t = (tid >= ofs) ? s[tid - ofs] : 0;
        __syncthreads(); s[tid] += t; __syncthreads();
    }
    if (i < n) rowptr[i] = s[tid] - v;
    if (tid == 255) bsum[blockIdx.x] = s[255];
}

__global__ __launch_bounds__(256) void k_scan2(int* __restrict__ bsum, int nb) {
    __shared__ int s[256];
    int tid = threadIdx.x;
    int v = (tid < nb) ? bsum[tid] : 0;
    s[tid] = v; __syncthreads();
    for (int ofs = 1; ofs < 256; ofs <<= 1) {
        int t = (tid >= ofs) ? s[tid - ofs] : 0;
        __syncthreads(); s[tid] += t; __syncthreads();
    }
    if (tid < nb) bsum[tid] = s[tid] - v;
}

__global__ __launch_bounds__(256) void k_scan3(int* __restrict__ rowptr, const int* __restrict__ bsum,
                                               int n, int e) {
    int i = blockIdx.x * 256 + threadIdx.x;
    if (i < n) rowptr[i] += bsum[i >> 8];
    if (i == n) rowptr[n] = e;
}

__global__ __launch_bounds__(256) void k_scatter(const int* __restrict__ src, const int* __restrict__ dst,
                                                 const float* __restrict__ invs, const int* __restrict__ rowptr,
                                                 int* __restrict__ cnt, int2* __restrict__ edge, int e) {
    int i = blockIdx.x * 256 + threadIdx.x;
    if (i >= e) return;
    int d = dst[i], sv = src[i];
    int pos = rowptr[d] + atomicAdd(&cnt[d], 1);
    edge[pos] = make_int2(sv, __float_as_int(invs[sv] * invs[d]));
}

// ---------------- fp32 -> bf16 cast (x -> z0) ----------------

__global__ __launch_bounds__(256) void k_cast(const float4* __restrict__ in, ushort4* __restrict__ out, int total4) {
    int i = blockIdx.x * 256 + threadIdx.x;
    if (i < total4) {
        float4 v = in[i];
        ushort4 o;
        o.x = f2bf(v.x); o.y = f2bf(v.y); o.z = f2bf(v.z); o.w = f2bf(v.w);
        out[i] = o;
    }
}

// ---------------- conv64 bf16: 1 wave/node, 16 lanes/edge (ushort4=8B), 16 edges in flight ----------------

__global__ __launch_bounds__(256) void k_conv64b(const ushort4* __restrict__ zin, const float4* __restrict__ h04,
                                                 ushort4* __restrict__ zout, const int* __restrict__ rowptr,
                                                 const int2* __restrict__ edge, int n) {
    int wid = (blockIdx.x * 256 + threadIdx.x) >> 6;   // node
    if (wid >= n) return;
    int lane = threadIdx.x & 63;
    int g = lane >> 4, c = lane & 15;                  // c: which ushort4 of the 16 in a row
    int e0 = rowptr[wid], e1 = rowptr[wid + 1];
    float a0 = 0.f, a1 = 0.f, a2 = 0.f, a3 = 0.f;
    for (int e = e0; e < e1; e += 16) {
        #pragma unroll
        for (int k = 0; k < 4; ++k) {
            int idx = e + k * 4 + g;
            bool ok = idx < e1;
            int2 p = edge[ok ? idx : e0];
            float w = ok ? __int_as_float(p.y) : 0.f;
            ushort4 v = zin[(size_t)p.x * 16 + c];
            a0 = fmaf(w, bf2f(v.x), a0);
            a1 = fmaf(w, bf2f(v.y), a1);
            a2 = fmaf(w, bf2f(v.z), a2);
            a3 = fmaf(w, bf2f(v.w), a3);
        }
    }
    a0 += __shfl_xor(a0, 16); a1 += __shfl_xor(a1, 16);
    a2 += __shfl_xor(a2, 16); a3 += __shfl_xor(a3, 16);
    a0 += __shfl_xor(a0, 32); a1 += __shfl_xor(a1, 32);
    a2 += __shfl_xor(a2, 32); a3 += __shfl_xor(a3, 32);
    if (lane < 16) {
        float4 h = h04[(size_t)wid * 16 + lane];
        ushort4 o;
        o.x = f2bf(a0 * DIFF + (1.f - DIFF) * h.x);
        o.y = f2bf(a1 * DIFF + (1.f - DIFF) * h.y);
        o.z = f2bf(a2 * DIFF + (1.f - DIFF) * h.z);
        o.w = f2bf(a3 * DIFF + (1.f - DIFF) * h.w);
        zout[(size_t)wid * 16 + lane] = o;
    }
}

// ---------------- conv16 (fp32, output path): 1 wave/node, 4 lanes/edge ----------------

__global__ __launch_bounds__(256) void k_conv16(const float4* __restrict__ zin4, const float4* __restrict__ g04,
                                                float4* __restrict__ zout4, const int* __restrict__ rowptr,
                                                const int2* __restrict__ edge, int n) {
    int wid = (blockIdx.x * 256 + threadIdx.x) >> 6;   // node
    if (wid >= n) return;
    int lane = threadIdx.x & 63;
    int g = lane >> 2, c = lane & 3;
    int e0 = rowptr[wid], e1 = rowptr[wid + 1];
    float4 acc; acc.x = acc.y = acc.z = acc.w = 0.f;
    for (int e = e0; e < e1; e += 32) {
        #pragma unroll
        for (int k = 0; k < 2; ++k) {
            int idx = e + k * 16 + g;
            bool ok = idx < e1;
            int2 p = edge[ok ? idx : e0];
            float w = ok ? __int_as_float(p.y) : 0.f;
            float4 v = zin4[(size_t)p.x * 4 + c];
            acc.x = fmaf(w, v.x, acc.x);
            acc.y = fmaf(w, v.y, acc.y);
            acc.z = fmaf(w, v.z, acc.z);
            acc.w = fmaf(w, v.w, acc.w);
        }
    }
    float4 t;
    t.x = __shfl_xor(acc.x, 4);  t.y = __shfl_xor(acc.y, 4);  t.z = __shfl_xor(acc.z, 4);  t.w = __shfl_xor(acc.w, 4);
    acc.x += t.x; acc.y += t.y; acc.z += t.z; acc.w += t.w;
    t.x = __shfl_xor(acc.x, 8);  t.y = __shfl_xor(acc.y, 8);  t.z = __shfl_xor(acc.z, 8);  t.w = __shfl_xor(acc.w, 8);
    acc.x += t.x; acc.y += t.y; acc.z += t.z; acc.w += t.w;
    t.x = __shfl_xor(acc.x, 16); t.y = __shfl_xor(acc.y, 16); t.z = __shfl_xor(acc.z, 16); t.w = __shfl_xor(acc.w, 16);
    acc.x += t.x; acc.y += t.y; acc.z += t.z; acc.w += t.w;
    t.x = __shfl_xor(acc.x, 32); t.y = __shfl_xor(acc.y, 32); t.z = __shfl_xor(acc.z, 32); t.w = __shfl_xor(acc.w, 32);
    acc.x += t.x; acc.y += t.y; acc.z += t.z; acc.w += t.w;
    if (lane < 4) {
        float4 h = g04[(size_t)wid * 4 + lane];
        float4 o;
        o.x = acc.x * DIFF + (1.f - DIFF) * h.x;
        o.y = acc.y * DIFF + (1.f - DIFF) * h.y;
        o.z = acc.z * DIFF + (1.f - DIFF) * h.z;
        o.w = acc.w * DIFF + (1.f - DIFF) * h.w;
        zout4[(size_t)wid * 4 + lane] = o;
    }
}

// ---------------- fused pair-MLP + node-MLP ----------------

__global__ __launch_bounds__(256) void k_pairmlp(const unsigned short* __restrict__ z1, const float* __restrict__ x,
                                                 const float* __restrict__ W1, const float* __restrict__ b1,
                                                 const float* __restrict__ W2, const float* __restrict__ b2,
                                                 const float* __restrict__ A1, const float* __restrict__ ab1,
                                                 const float* __restrict__ A2, const float* __restrict__ ab2,
                                                 const float* __restrict__ emb,
                                                 float* __restrict__ g0, int n) {
    __shared__ float W2s[64 * 16];           // 4 KB
    __shared__ float in_s[32][128];          // 16 KB
    __shared__ float hid[32 * 65];           // 8.3 KB
    __shared__ float eA1[64 * ADJ_HID];      // 2.8 KB
    __shared__ float a0s[ADJ_HID], a1s[ADJ_HID], a2s[ADJ_HID];
    __shared__ float ab2s;

    int tid  = threadIdx.x;
    int base = blockIdx.x * 32;

    // ---- phase A: small tables ----
    #pragma unroll
    for (int k = 0; k < 4; ++k)  W2s[tid + k * 256] = W2[tid + k * 256];
    if (tid < ADJ_HID) { a0s[tid] = A1[tid]; a1s[tid] = A1[ADJ_HID + tid]; a2s[tid] = A2[tid]; }
    if (tid == 0) ab2s = ab2[0];
    for (int idx = tid; idx < 64 * ADJ_HID; idx += 256) {
        int c = idx / ADJ_HID, h = idx - c * ADJ_HID;
        float s = ab1[h];
        #pragma unroll
        for (int j = 0; j < EMB_DIM; j++) s = fmaf(emb[c * EMB_DIM + j], A1[(2 + j) * ADJ_HID + h], s);
        eA1[idx] = s;
    }
    __syncthreads();

    // ---- phase B: pair MLP ----
    #pragma unroll
    for (int k = 0; k < 8; ++k) {
        int idx = tid + k * 256;             // 0..2047
        int nl = idx >> 6, c = idx & 63;
        int node = base + nl; if (node > n - 1) node = n - 1;
        float zv = bf2f(z1[(size_t)node * 64 + c]);
        float xv = x[(size_t)node * 64 + c];
        float out = ab2s;
        #pragma unroll
        for (int h = 0; h < ADJ_HID; h++) {
            float t = fmaf(zv, a0s[h], fmaf(xv, a1s[h], eA1[c * ADJ_HID + h]));
            t = fmaxf(t, 0.f);
            out = fmaf(t, a2s[h], out);
        }
        in_s[nl][c]      = out * 0.5f;
        in_s[nl][64 + c] = xv;
    }
    __syncthreads();

    // ---- phase C: GEMM1, W1 streamed from global (L2-resident) ----
    {
        int lane = tid & 63, wv = tid >> 6;
        int nb0 = wv * 8;
        float bv = b1[lane];
        float acc[8];
        #pragma unroll
        for (int j = 0; j < 8; ++j) acc[j] = bv;
        #pragma unroll 8
        for (int rb = 0; rb < 128; rb += 4) {
            float w0 = W1[(rb    ) * 64 + lane];
            float w1 = W1[(rb + 1) * 64 + lane];
            float w2 = W1[(rb + 2) * 64 + lane];
            float w3 = W1[(rb + 3) * 64 + lane];
            #pragma unroll
            for (int j = 0; j < 8; ++j) {
                float4 iv = *(const float4*)&in_s[nb0 + j][rb];
                acc[j] = fmaf(iv.w, w3, fmaf(iv.z, w2, fmaf(iv.y, w1, fmaf(iv.x, w0, acc[j]))));
            }
        }
        #pragma unroll
        for (int j = 0; j < 8; ++j) hid[(nb0 + j) * 65 + lane] = fmaxf(acc[j], 0.f);
    }
    __syncthreads();

    // ---- phase D: GEMM2 ----
    {
        int c  = tid & 15;
        int nl = tid >> 4;
        float ac0 = b2[c], ac1 = ac0;
        #pragma unroll
        for (int h = 0; h < 64; ++h) {
            float w = W2s[h * 16 + c];
            ac0 = fmaf(hid[nl * 65 + h],        w, ac0);
            ac1 = fmaf(hid[(nl + 16) * 65 + h], w, ac1);
        }
        int n0 = base + nl, n1 = base + nl + 16;
        if (n0 < n) g0[(size_t)n0 * 16 + c] = ac0;
        if (n1 < n) g0[(size_t)n1 * 16 + c] = ac1;
    }
}

// ---------------- launch ----------------

extern "C" void kernel_launch(void* const* d_in, const int* in_sizes, int n_in,
                              void* d_out, int out_size, void* d_ws, size_t ws_size,
                              hipStream_t stream) {
    const float* x   = (const float*)d_in[0];
    const int*   src = (const int*)d_in[1];
    const int*   dst = (const int*)d_in[2];
    const float* W1  = (const float*)d_in[3];
    const float* b1  = (const float*)d_in[4];
    const float* W2  = (const float*)d_in[5];
    const float* b2  = (const float*)d_in[6];
    const float* A1  = (const float*)d_in[7];
    const float* ab1 = (const float*)d_in[8];
    const float* A2  = (const float*)d_in[9];
    const float* ab2 = (const float*)d_in[10];
    const float* emb = (const float*)d_in[11];

    int n = in_sizes[0] / FEATS;   // 50000
    int e = in_sizes[1];           // 800000

    char* ws = (char*)d_ws;
    size_t off = 0;
    auto alloc = [&](size_t bytes) {
        void* p = ws + off;
        off += bytes;
        off = (off + 255) & ~(size_t)255;
        return p;
    };

    int*     deg    = (int*)    alloc((size_t)n * 4);
    float*   invs   = (float*)  alloc((size_t)n * 4);
    int*     rowptr = (int*)    alloc((size_t)(n + 1) * 4);
    int*     cnt    = (int*)    alloc((size_t)n * 4);
    int*     bsum   = (int*)    alloc(1024);
    int2*    edge   = (int2*)   alloc((size_t)e * 8 + 256);
    ushort4* zbA    = (ushort4*)alloc((size_t)n * 64 * 2);
    ushort4* zbB    = (ushort4*)alloc((size_t)n * 64 * 2);
    float*   g0     = (float*)  alloc((size_t)n * 16 * 4);
    float*   g1     = (float*)  alloc((size_t)n * 16 * 4);
    float*   g2     = (float*)  alloc((size_t)n * 16 * 4);

    hipMemsetAsync(deg, 0, (size_t)n * 4, stream);
    hipMemsetAsync(cnt, 0, (size_t)n * 4, stream);

    int eb = (e + 255) / 256;
    int nb = (n + 255) / 256;

    k_deg    <<<eb, 256, 0, stream>>>(dst, deg, e);
    k_invs   <<<nb, 256, 0, stream>>>(deg, invs, n);
    k_scan1  <<<nb, 256, 0, stream>>>(deg, rowptr, bsum, n);
    k_scan2  <<<1, 256, 0, stream>>>(bsum, nb);
    k_scan3  <<<(n + 256) / 256, 256, 0, stream>>>(rowptr, bsum, n, e);
    k_scatter<<<eb, 256, 0, stream>>>(src, dst, invs, rowptr, cnt, edge, e);

    // cast x -> bf16 z0
    int total4 = n * 16;
    k_cast<<<(total4 + 255) / 256, 256, 0, stream>>>((const float4*)x, zbA, total4);

    int nwb = (n + 3) / 4;   // 4 waves (nodes) per 256-thread block

    // diffusion over features (10 iters), bf16 state
    const ushort4* zin = zbA;
    ushort4* zout = zbB;
    for (int it = 0; it < 10; ++it) {
        k_conv64b<<<nwb, 256, 0, stream>>>(zin, (const float4*)x, zout, rowptr, edge, n);
        zin  = zout;
        zout = (zout == zbA) ? zbB : zbA;
    }
    const unsigned short* z1 = (const unsigned short*)zin;

    k_pairmlp<<<(n + 31) / 32, 256, 0, stream>>>(z1, x, W1, b1, W2, b2,
                                                 A1, ab1, A2, ab2, emb, g0, n);

    // diffusion over logits (10 iters, fp32)
    const float* gin = g0;
    float* gout = g1;
    for (int it = 0; it < 10; ++it) {
        float* out = (it == 9) ? (float*)d_out : gout;
        k_conv16<<<nwb, 256, 0, stream>>>((const float4*)gin, (const float4*)g0, (float4*)out,
                                          rowptr, edge, n);
        gin  = out;
        gout = (gout == g1) ? g2 : g1;
    }
}

// Round 6
// 683.334 us; speedup vs baseline: 1.4262x; 1.0334x over previous
//
#include <hip/hip_runtime.h>

#define FEATS    64
#define CLASSES  16
#define EMB_DIM  7
#define ADJ_HID  11
#define DIFF     0.9f

__device__ inline float bf2f(unsigned short u) {
    return __uint_as_float(((unsigned int)u) << 16);
}
__device__ inline unsigned short f2bf(float f) {
    unsigned int u = __float_as_uint(f);
    return (unsigned short)((u + 0x7FFFu + ((u >> 16) & 1u)) >> 16);
}

// ---------------- graph preprocessing ----------------

__global__ __launch_bounds__(256) void k_deg(const int* __restrict__ dst, int* __restrict__ deg, int e) {
    int i = blockIdx.x * 256 + threadIdx.x;
    if (i < e) atomicAdd(&deg[dst[i]], 1);
}

__global__ __launch_bounds__(256) void k_invs(const int* __restrict__ deg, float* __restrict__ invs, int n) {
    int i = blockIdx.x * 256 + threadIdx.x;
    if (i < n) { int d = deg[i]; invs[i] = d > 0 ? rsqrtf((float)d) : 0.f; }
}

__global__ __launch_bounds__(256) void k_scan1(const int* __restrict__ deg, int* __restrict__ rowptr,
                                               int* __restrict__ bsum, int n) {
    __shared__ int s[256];
    int tid = threadIdx.x;
    int i = blockIdx.x * 256 + tid;
    int v = (i < n) ? deg[i] : 0;
    s[tid] = v; __syncthreads();
    for (int ofs = 1; ofs < 256; ofs <<= 1) {
        int t = (tid >= ofs) ? s[tid - ofs] : 0;
        __syncthreads(); s[tid] += t; __syncthreads();
    }
    if (i < n) rowptr[i] = s[tid] - v;
    if (tid == 255) bsum[blockIdx.x] = s[255];
}

__global__ __launch_bounds__(256) void k_scan2(int* __restrict__ bsum, int nb) {
    __shared__ int s[256];
    int tid = threadIdx.x;
    int v = (tid < nb) ? bsum[tid] : 0;
    s[tid] = v; __syncthreads();
    for (int ofs = 1; ofs < 256; ofs <<= 1) {
        int t = (tid >= ofs) ? s[tid - ofs] : 0;
        __syncthreads(); s[tid] += t; __syncthreads();
    }
    if (tid < nb) bsum[tid] = s[tid] - v;
}

__global__ __launch_bounds__(256) void k_scan3(int* __restrict__ rowptr, const int* __restrict__ bsum,
                                               int n, int e) {
    int i = blockIdx.x * 256 + threadIdx.x;
    if (i < n) rowptr[i] += bsum[i >> 8];
    if (i == n) rowptr[n] = e;
}

__global__ __launch_bounds__(256) void k_scatter(const int* __restrict__ src, const int* __restrict__ dst,
                                                 const float* __restrict__ invs, const int* __restrict__ rowptr,
                                                 int* __restrict__ cnt, int2* __restrict__ edge, int e) {
    int i = blockIdx.x * 256 + threadIdx.x;
    if (i >= e) return;
    int d = dst[i], sv = src[i];
    int pos = rowptr[d] + atomicAdd(&cnt[d], 1);
    edge[pos] = make_int2(sv, __float_as_int(invs[sv] * invs[d]));
}

// ---------------- fp32 -> bf16 cast (x -> xb) ----------------

__global__ __launch_bounds__(256) void k_cast(const float4* __restrict__ in, ushort4* __restrict__ out, int total4) {
    int i = blockIdx.x * 256 + threadIdx.x;
    if (i < total4) {
        float4 v = in[i];
        ushort4 o;
        o.x = f2bf(v.x); o.y = f2bf(v.y); o.z = f2bf(v.z); o.w = f2bf(v.w);
        out[i] = o;
    }
}

// ---------------- conv64 bf16: 1 wave/node, 16 lanes/edge (ushort4=8B), 16 edges in flight ----------------

__global__ __launch_bounds__(256) void k_conv64b(const ushort4* __restrict__ zin, const ushort4* __restrict__ h0b,
                                                 ushort4* __restrict__ zout, const int* __restrict__ rowptr,
                                                 const int2* __restrict__ edge, int n) {
    int wid = (blockIdx.x * 256 + threadIdx.x) >> 6;   // node
    if (wid >= n) return;
    int lane = threadIdx.x & 63;
    int g = lane >> 4, c = lane & 15;                  // c: which ushort4 of the 16 in a row
    int e0 = rowptr[wid], e1 = rowptr[wid + 1];
    float a0 = 0.f, a1 = 0.f, a2 = 0.f, a3 = 0.f;
    for (int e = e0; e < e1; e += 16) {
        #pragma unroll
        for (int k = 0; k < 4; ++k) {
            int idx = e + k * 4 + g;
            bool ok = idx < e1;
            int2 p = edge[ok ? idx : e0];
            float w = ok ? __int_as_float(p.y) : 0.f;
            ushort4 v = zin[(size_t)p.x * 16 + c];
            a0 = fmaf(w, bf2f(v.x), a0);
            a1 = fmaf(w, bf2f(v.y), a1);
            a2 = fmaf(w, bf2f(v.z), a2);
            a3 = fmaf(w, bf2f(v.w), a3);
        }
    }
    a0 += __shfl_xor(a0, 16); a1 += __shfl_xor(a1, 16);
    a2 += __shfl_xor(a2, 16); a3 += __shfl_xor(a3, 16);
    a0 += __shfl_xor(a0, 32); a1 += __shfl_xor(a1, 32);
    a2 += __shfl_xor(a2, 32); a3 += __shfl_xor(a3, 32);
    if (lane < 16) {
        ushort4 h4 = h0b[(size_t)wid * 16 + lane];
        ushort4 o;
        o.x = f2bf(a0 * DIFF + (1.f - DIFF) * bf2f(h4.x));
        o.y = f2bf(a1 * DIFF + (1.f - DIFF) * bf2f(h4.y));
        o.z = f2bf(a2 * DIFF + (1.f - DIFF) * bf2f(h4.z));
        o.w = f2bf(a3 * DIFF + (1.f - DIFF) * bf2f(h4.w));
        zout[(size_t)wid * 16 + lane] = o;
    }
}

// ---------------- conv16 (fp32, output path): 1 wave/node, 4 lanes/edge ----------------

__global__ __launch_bounds__(256) void k_conv16(const float4* __restrict__ zin4, const float4* __restrict__ g04,
                                                float4* __restrict__ zout4, const int* __restrict__ rowptr,
                                                const int2* __restrict__ edge, int n) {
    int wid = (blockIdx.x * 256 + threadIdx.x) >> 6;   // node
    if (wid >= n) return;
    int lane = threadIdx.x & 63;
    int g = lane >> 2, c = lane & 3;
    int e0 = rowptr[wid], e1 = rowptr[wid + 1];
    float4 acc; acc.x = acc.y = acc.z = acc.w = 0.f;
    for (int e = e0; e < e1; e += 32) {
        #pragma unroll
        for (int k = 0; k < 2; ++k) {
            int idx = e + k * 16 + g;
            bool ok = idx < e1;
            int2 p = edge[ok ? idx : e0];
            float w = ok ? __int_as_float(p.y) : 0.f;
            float4 v = zin4[(size_t)p.x * 4 + c];
            acc.x = fmaf(w, v.x, acc.x);
            acc.y = fmaf(w, v.y, acc.y);
            acc.z = fmaf(w, v.z, acc.z);
            acc.w = fmaf(w, v.w, acc.w);
        }
    }
    float4 t;
    t.x = __shfl_xor(acc.x, 4);  t.y = __shfl_xor(acc.y, 4);  t.z = __shfl_xor(acc.z, 4);  t.w = __shfl_xor(acc.w, 4);
    acc.x += t.x; acc.y += t.y; acc.z += t.z; acc.w += t.w;
    t.x = __shfl_xor(acc.x, 8);  t.y = __shfl_xor(acc.y, 8);  t.z = __shfl_xor(acc.z, 8);  t.w = __shfl_xor(acc.w, 8);
    acc.x += t.x; acc.y += t.y; acc.z += t.z; acc.w += t.w;
    t.x = __shfl_xor(acc.x, 16); t.y = __shfl_xor(acc.y, 16); t.z = __shfl_xor(acc.z, 16); t.w = __shfl_xor(acc.w, 16);
    acc.x += t.x; acc.y += t.y; acc.z += t.z; acc.w += t.w;
    t.x = __shfl_xor(acc.x, 32); t.y = __shfl_xor(acc.y, 32); t.z = __shfl_xor(acc.z, 32); t.w = __shfl_xor(acc.w, 32);
    acc.x += t.x; acc.y += t.y; acc.z += t.z; acc.w += t.w;
    if (lane < 4) {
        float4 h = g04[(size_t)wid * 4 + lane];
        float4 o;
        o.x = acc.x * DIFF + (1.f - DIFF) * h.x;
        o.y = acc.y * DIFF + (1.f - DIFF) * h.y;
        o.z = acc.z * DIFF + (1.f - DIFF) * h.z;
        o.w = acc.w * DIFF + (1.f - DIFF) * h.w;
        zout4[(size_t)wid * 4 + lane] = o;
    }
}

// ---------------- fused pair-MLP + node-MLP, persistent blocks ----------------
// grid = 512 (2 blocks/CU). Stage W1 (32KB) + W2 + eA1T into LDS ONCE,
// then loop over 32-node tiles: B (pair MLP -> in_s), C (GEMM1), D (GEMM2).

#define PM_GRID 512

__global__ __launch_bounds__(256) void k_pairmlp(const unsigned short* __restrict__ z1, const float* __restrict__ x,
                                                 const float* __restrict__ W1, const float* __restrict__ b1,
                                                 const float* __restrict__ W2, const float* __restrict__ b2,
                                                 const float* __restrict__ A1, const float* __restrict__ ab1,
                                                 const float* __restrict__ A2, const float* __restrict__ ab2,
                                                 const float* __restrict__ emb,
                                                 float* __restrict__ g0, int n, int ntiles) {
    __shared__ float W1s[128 * 64];          // 32 KB, [r][h]
    __shared__ float W2s[64 * 16];           // 4 KB
    __shared__ float in_s[32][128];          // 16 KB
    __shared__ float hid[32 * 65];           // 8.3 KB
    __shared__ float eA1T[ADJ_HID * 64];     // 2.8 KB, [h][c]
    __shared__ float a0s[ADJ_HID], a1s[ADJ_HID], a2s[ADJ_HID];
    __shared__ float ab2s;

    int tid = threadIdx.x;
    const ushort4* z4p = (const ushort4*)z1;
    const float4*  x4p = (const float4*)x;

    // ---- stage weights once per block ----
    #pragma unroll
    for (int k = 0; k < 32; ++k) W1s[tid + k * 256] = W1[tid + k * 256];
    #pragma unroll
    for (int k = 0; k < 4; ++k)  W2s[tid + k * 256] = W2[tid + k * 256];
    if (tid < ADJ_HID) { a0s[tid] = A1[tid]; a1s[tid] = A1[ADJ_HID + tid]; a2s[tid] = A2[tid]; }
    if (tid == 0) ab2s = ab2[0];
    for (int idx = tid; idx < ADJ_HID * 64; idx += 256) {
        int h = idx >> 6, c = idx & 63;
        float s = ab1[h];
        #pragma unroll
        for (int j = 0; j < EMB_DIM; j++) s = fmaf(emb[c * EMB_DIM + j], A1[(2 + j) * ADJ_HID + h], s);
        eA1T[idx] = s;
    }
    __syncthreads();

    for (int tile = blockIdx.x; tile < ntiles; tile += PM_GRID) {
        int base = tile * 32;

        // ---- phase B: pair MLP, 4 feats per thread-chunk, vectorized loads ----
        #pragma unroll
        for (int j = 0; j < 2; ++j) {
            int e4 = tid + j * 256;              // 0..511
            int nl = e4 >> 4, c4 = e4 & 15;      // node-local, float4-group
            int node = base + nl; if (node > n - 1) node = n - 1;
            ushort4 z4 = z4p[(size_t)node * 16 + c4];
            float4  x4 = x4p[(size_t)node * 16 + c4];
            float zf0 = bf2f(z4.x), zf1 = bf2f(z4.y), zf2 = bf2f(z4.z), zf3 = bf2f(z4.w);
            float o0 = ab2s, o1 = ab2s, o2 = ab2s, o3 = ab2s;
            #pragma unroll
            for (int h = 0; h < ADJ_HID; h++) {
                float a0 = a0s[h], a1 = a1s[h], a2 = a2s[h];
                float4 ee = *(const float4*)&eA1T[h * 64 + c4 * 4];
                float t;
                t = fmaf(zf0, a0, fmaf(x4.x, a1, ee.x)); t = fmaxf(t, 0.f); o0 = fmaf(t, a2, o0);
                t = fmaf(zf1, a0, fmaf(x4.y, a1, ee.y)); t = fmaxf(t, 0.f); o1 = fmaf(t, a2, o1);
                t = fmaf(zf2, a0, fmaf(x4.z, a1, ee.z)); t = fmaxf(t, 0.f); o2 = fmaf(t, a2, o2);
                t = fmaf(zf3, a0, fmaf(x4.w, a1, ee.w)); t = fmaxf(t, 0.f); o3 = fmaf(t, a2, o3);
            }
            *(float4*)&in_s[nl][c4 * 4]      = make_float4(o0 * 0.5f, o1 * 0.5f, o2 * 0.5f, o3 * 0.5f);
            *(float4*)&in_s[nl][64 + c4 * 4] = x4;
        }
        __syncthreads();

        // ---- phase C: GEMM1 from LDS W1s ----
        {
            int lane = tid & 63, wv = tid >> 6;
            int nb0 = wv * 8;
            float bv = b1[lane];
            float acc[8];
            #pragma unroll
            for (int j = 0; j < 8; ++j) acc[j] = bv;
            #pragma unroll 8
            for (int rb = 0; rb < 128; rb += 4) {
                float w0 = W1s[(rb    ) * 64 + lane];
                float w1 = W1s[(rb + 1) * 64 + lane];
                float w2 = W1s[(rb + 2) * 64 + lane];
                float w3 = W1s[(rb + 3) * 64 + lane];
                #pragma unroll
                for (int j = 0; j < 8; ++j) {
                    float4 iv = *(const float4*)&in_s[nb0 + j][rb];
                    acc[j] = fmaf(iv.w, w3, fmaf(iv.z, w2, fmaf(iv.y, w1, fmaf(iv.x, w0, acc[j]))));
                }
            }
            #pragma unroll
            for (int j = 0; j < 8; ++j) hid[(nb0 + j) * 65 + lane] = fmaxf(acc[j], 0.f);
        }
        __syncthreads();

        // ---- phase D: GEMM2 ----
        {
            int c  = tid & 15;
            int nl = tid >> 4;
            float ac0 = b2[c], ac1 = ac0;
            #pragma unroll
            for (int h = 0; h < 64; ++h) {
                float w = W2s[h * 16 + c];
                ac0 = fmaf(hid[nl * 65 + h],        w, ac0);
                ac1 = fmaf(hid[(nl + 16) * 65 + h], w, ac1);
            }
            int n0 = base + nl, n1 = base + nl + 16;
            if (n0 < n) g0[(size_t)n0 * 16 + c] = ac0;
            if (n1 < n) g0[(size_t)n1 * 16 + c] = ac1;
        }
        __syncthreads();   // protect in_s/hid before next tile
    }
}

// ---------------- launch ----------------

extern "C" void kernel_launch(void* const* d_in, const int* in_sizes, int n_in,
                              void* d_out, int out_size, void* d_ws, size_t ws_size,
                              hipStream_t stream) {
    const float* x   = (const float*)d_in[0];
    const int*   src = (const int*)d_in[1];
    const int*   dst = (const int*)d_in[2];
    const float* W1  = (const float*)d_in[3];
    const float* b1  = (const float*)d_in[4];
    const float* W2  = (const float*)d_in[5];
    const float* b2  = (const float*)d_in[6];
    const float* A1  = (const float*)d_in[7];
    const float* ab1 = (const float*)d_in[8];
    const float* A2  = (const float*)d_in[9];
    const float* ab2 = (const float*)d_in[10];
    const float* emb = (const float*)d_in[11];

    int n = in_sizes[0] / FEATS;   // 50000
    int e = in_sizes[1];           // 800000

    char* ws = (char*)d_ws;
    size_t off = 0;
    auto alloc = [&](size_t bytes) {
        void* p = ws + off;
        off += bytes;
        off = (off + 255) & ~(size_t)255;
        return p;
    };

    int*     deg    = (int*)    alloc((size_t)n * 4);
    float*   invs   = (float*)  alloc((size_t)n * 4);
    int*     rowptr = (int*)    alloc((size_t)(n + 1) * 4);
    int*     cnt    = (int*)    alloc((size_t)n * 4);
    int*     bsum   = (int*)    alloc(1024);
    int2*    edge   = (int2*)   alloc((size_t)e * 8 + 256);
    ushort4* xb     = (ushort4*)alloc((size_t)n * 64 * 2);
    ushort4* zbA    = (ushort4*)alloc((size_t)n * 64 * 2);
    ushort4* zbB    = (ushort4*)alloc((size_t)n * 64 * 2);
    float*   g0     = (float*)  alloc((size_t)n * 16 * 4);
    float*   g1     = (float*)  alloc((size_t)n * 16 * 4);
    float*   g2     = (float*)  alloc((size_t)n * 16 * 4);

    hipMemsetAsync(deg, 0, (size_t)n * 4, stream);
    hipMemsetAsync(cnt, 0, (size_t)n * 4, stream);

    int eb = (e + 255) / 256;
    int nb = (n + 255) / 256;

    k_deg    <<<eb, 256, 0, stream>>>(dst, deg, e);
    k_invs   <<<nb, 256, 0, stream>>>(deg, invs, n);
    k_scan1  <<<nb, 256, 0, stream>>>(deg, rowptr, bsum, n);
    k_scan2  <<<1, 256, 0, stream>>>(bsum, nb);
    k_scan3  <<<(n + 256) / 256, 256, 0, stream>>>(rowptr, bsum, n, e);
    k_scatter<<<eb, 256, 0, stream>>>(src, dst, invs, rowptr, cnt, edge, e);

    // cast x -> bf16 (serves as z0 and as h0 for the bf16 diffusion)
    int total4 = n * 16;
    k_cast<<<(total4 + 255) / 256, 256, 0, stream>>>((const float4*)x, xb, total4);

    int nwb = (n + 3) / 4;   // 4 waves (nodes) per 256-thread block

    // diffusion over features (10 iters), bf16 state
    const ushort4* zin = xb;
    ushort4* zout = zbA;
    for (int it = 0; it < 10; ++it) {
        k_conv64b<<<nwb, 256, 0, stream>>>(zin, xb, zout, rowptr, edge, n);
        zin  = zout;
        zout = (it == 0) ? zbB : ((zout == zbA) ? zbB : zbA);
    }
    const unsigned short* z1 = (const unsigned short*)zin;

    int ntiles = (n + 31) / 32;
    k_pairmlp<<<PM_GRID, 256, 0, stream>>>(z1, x, W1, b1, W2, b2,
                                           A1, ab1, A2, ab2, emb, g0, n, ntiles);

    // diffusion over logits (10 iters, fp32)
    const float* gin = g0;
    float* gout = g1;
    for (int it = 0; it < 10; ++it) {
        float* out = (it == 9) ? (float*)d_out : gout;
        k_conv16<<<nwb, 256, 0, stream>>>((const float4*)gin, (const float4*)g0, (float4*)out,
                                          rowptr, edge, n);
        gin  = out;
        gout = (gout == g1) ? g2 : g1;
    }
}